// Round 4
// baseline (526.128 us; speedup 1.0000x reference)
//
#include <hip/hip_runtime.h>
#include <math.h>

// Problem constants (B,S,D,H fixed by the reference)
constexpr int Bc = 2, Sc = 2048, Dc = 2048, Hc = 16, DHc = 128;
constexpr int Mc = Bc * Sc;   // 4096 rows of x
constexpr int N3 = 3 * Dc;    // 6144

typedef short     s16x8  __attribute__((ext_vector_type(8)));
typedef float     f32x4  __attribute__((ext_vector_type(4)));
typedef unsigned short ushortv8 __attribute__((ext_vector_type(8)));

__device__ __forceinline__ unsigned short f2bf(float f) {
  unsigned u = __float_as_uint(f);
  u += 0x7fffu + ((u >> 16) & 1u);       // RNE
  return (unsigned short)(u >> 16);
}
__device__ __forceinline__ float bf2f(unsigned short h) {
  return __uint_as_float(((unsigned)h) << 16);
}

// Async global->LDS, 16B per lane. LDS base must be wave-uniform; hardware
// writes base + lane*16. Global address is per-lane. [m97/m104 semantics]
__device__ __forceinline__ void gld_lds16(const unsigned short* g, unsigned short* l) {
  __builtin_amdgcn_global_load_lds(
      (const __attribute__((address_space(1))) void*)g,
      (__attribute__((address_space(3))) void*)l, 16, 0, 0);
}

// DPP helpers: reduction across 16-lane rows without touching the LDS pipe.
template<int CTRL>
__device__ __forceinline__ float dppf(float x) {
  return __int_as_float(
      __builtin_amdgcn_update_dpp(0, __float_as_int(x), CTRL, 0xF, 0xF, true));
}
__device__ __forceinline__ float rowmax16(float v) {
  v = fmaxf(v, dppf<0xB1>(v));    // xor1: quad_perm(1,0,3,2)
  v = fmaxf(v, dppf<0x4E>(v));    // xor2: quad_perm(2,3,0,1)
  v = fmaxf(v, dppf<0x141>(v));   // xor4: row_half_mirror
  v = fmaxf(v, dppf<0x140>(v));   // xor8: row_mirror
  return v;
}
__device__ __forceinline__ float rowsum16(float v) {
  v += dppf<0xB1>(v);
  v += dppf<0x4E>(v);
  v += dppf<0x141>(v);
  v += dppf<0x140>(v);
  return v;
}

// ---------------------------------------------------------------------------
// RoPE cos/sin tables: [S][64] each.
// ---------------------------------------------------------------------------
__global__ void rope_table_kernel(float* __restrict__ cosT, float* __restrict__ sinT) {
  int idx = blockIdx.x * 256 + threadIdx.x;   // S*64 = 131072 total
  int s = idx >> 6, j = idx & 63;
  float inv = powf(10000.0f, -(float)(2 * j) / 128.0f);
  float a = (float)s * inv;
  cosT[idx] = cosf(a);
  sinT[idx] = sinf(a);
}

// ---------------------------------------------------------------------------
// fp32 -> bf16 elementwise (x). 8 elements/thread.
// ---------------------------------------------------------------------------
__global__ void cvt_bf16(const float* __restrict__ in, unsigned short* __restrict__ outp) {
  size_t i = ((size_t)blockIdx.x * 256 + threadIdx.x) * 8;
  float4 a = *(const float4*)&in[i];
  float4 b = *(const float4*)&in[i + 4];
  ushortv8 o;
  o[0] = f2bf(a.x); o[1] = f2bf(a.y); o[2] = f2bf(a.z); o[3] = f2bf(a.w);
  o[4] = f2bf(b.x); o[5] = f2bf(b.y); o[6] = f2bf(b.z); o[7] = f2bf(b.w);
  *(ushortv8*)&outp[i] = o;
}

// ---------------------------------------------------------------------------
// fp32 [R][C] -> bf16 [C][R] transpose-convert via 64x64 LDS tile.
// ---------------------------------------------------------------------------
__global__ __launch_bounds__(256)
void cvt_transpose(const float* __restrict__ in, unsigned short* __restrict__ outp,
                   int R, int C) {
  __shared__ float Ls[64][69];
  const int nTc = C >> 6;
  const int tc = blockIdx.x % nTc, tr = blockIdx.x / nTc;
  const int r0 = tr << 6, c0 = tc << 6;
#pragma unroll
  for (int i = 0; i < 4; ++i) {
    int id = threadIdx.x + 256 * i;        // 0..1023
    int row = id >> 4, col = (id & 15) << 2;
    float4 v = *(const float4*)&in[(size_t)(r0 + row) * C + c0 + col];
    Ls[row][col] = v.x; Ls[row][col + 1] = v.y;
    Ls[row][col + 2] = v.z; Ls[row][col + 3] = v.w;
  }
  __syncthreads();
#pragma unroll
  for (int i = 0; i < 2; ++i) {
    int id = threadIdx.x + 256 * i;        // 0..511
    int crow = id >> 3, rcol = (id & 7) << 3;
    ushortv8 o;
#pragma unroll
    for (int jj = 0; jj < 8; ++jj) o[jj] = f2bf(Ls[rcol + jj][crow]);
    *(ushortv8*)&outp[(size_t)(c0 + crow) * R + r0 + rcol] = o;
  }
}

// ---------------------------------------------------------------------------
// bf16 MFMA GEMM, C[M,N] = A[M,2048] @ Bt[N,2048]^T + bias.
// m97 structure + XCD-aware block swizzle (T1; grid%8==0 -> bijective).
// ---------------------------------------------------------------------------
template<int EPI>
__global__ __launch_bounds__(256)
void gemm_bt(const unsigned short* __restrict__ A, const unsigned short* __restrict__ Bt,
             const float* __restrict__ bias, unsigned short* __restrict__ Qo,
             unsigned short* __restrict__ Ko, unsigned short* __restrict__ Vo,
             float* __restrict__ outF, int Ndim)
{
  constexpr int Kd = 2048;
  __shared__ unsigned short As[128 * 32];
  __shared__ unsigned short Bs[128 * 32];
  const int t = threadIdx.x;
  const int w = t >> 6, l = t & 63;
  const int l15 = l & 15, g = l >> 4;
  const int wr = w >> 1, wc = w & 1;
  // XCD swizzle: chunk the linearized grid per XCD (8 XCDs; nwg % 8 == 0)
  const int nwg = gridDim.x * gridDim.y;
  const int flat = blockIdx.y * gridDim.x + blockIdx.x;
  const int swz = (flat & 7) * (nwg >> 3) + (flat >> 3);
  const int m0 = (swz / gridDim.x) * 128, n0 = (swz % gridDim.x) * 128;
  const int srow = l >> 2;           // staging: row within 16-row group
  const int scol = (l & 3) * 8;      // staging: k-element offset (16B)

  f32x4 acc[4][4];
#pragma unroll
  for (int mi = 0; mi < 4; ++mi)
#pragma unroll
    for (int ni = 0; ni < 4; ++ni) acc[mi][ni] = (f32x4){0.f, 0.f, 0.f, 0.f};

  for (int k0 = 0; k0 < Kd; k0 += 32) {
    __syncthreads();                 // previous iter's LDS reads drained
#pragma unroll
    for (int j = 0; j < 2; ++j) {
      int rowg = (w * 2 + j) * 16 + srow;
      gld_lds16(&A[(size_t)(m0 + rowg) * Kd + k0 + scol], &As[(w * 2 + j) * 512]);
      gld_lds16(&Bt[(size_t)(n0 + rowg) * Kd + k0 + scol], &Bs[(w * 2 + j) * 512]);
    }
    __syncthreads();                 // vmcnt(0) drain -> LDS tile ready

    s16x8 af[4], bf[4];
#pragma unroll
    for (int mi = 0; mi < 4; ++mi)
      af[mi] = *(const s16x8*)&As[(wr * 64 + mi * 16 + l15) * 32 + g * 8];
#pragma unroll
    for (int ni = 0; ni < 4; ++ni)
      bf[ni] = *(const s16x8*)&Bs[(wc * 64 + ni * 16 + l15) * 32 + g * 8];
#pragma unroll
    for (int mi = 0; mi < 4; ++mi)
#pragma unroll
      for (int ni = 0; ni < 4; ++ni)
        acc[mi][ni] = __builtin_amdgcn_mfma_f32_16x16x32_bf16(af[mi], bf[ni], acc[mi][ni], 0, 0, 0);
  }

  if (EPI == 0) {
    const int part = n0 >> 11;
    const int h = (n0 >> 7) & 15;
    unsigned short* outp = (part == 0) ? Qo : (part == 1 ? Ko : Vo);
#pragma unroll
    for (int mi = 0; mi < 4; ++mi) {
#pragma unroll
      for (int r = 0; r < 4; ++r) {
        int row = m0 + wr * 64 + mi * 16 + g * 4 + r;
        int b_ = row >> 11, s_ = row & 2047;
        unsigned short* dst = outp + (((size_t)(b_ * Hc + h) * Sc + s_) << 7);
#pragma unroll
        for (int ni = 0; ni < 4; ++ni) {
          int col = wc * 64 + ni * 16 + l15;
          dst[col] = f2bf(acc[mi][ni][r] + bias[n0 + col]);
        }
      }
    }
  } else {
#pragma unroll
    for (int mi = 0; mi < 4; ++mi) {
#pragma unroll
      for (int r = 0; r < 4; ++r) {
        int row = m0 + wr * 64 + mi * 16 + g * 4 + r;
#pragma unroll
        for (int ni = 0; ni < 4; ++ni) {
          int col = wc * 64 + ni * 16 + l15;
          outF[(size_t)row * Ndim + n0 + col] = acc[mi][ni][r] + bias[n0 + col];
        }
      }
    }
  }
}

// ---------------------------------------------------------------------------
// In-place RoPE on bf16 Q,K. Q pre-scaled by log2(e)/sqrt(DH): folds the
// softmax scale AND the exp->exp2 conversion into Q (saves a VALU mul per
// exponential in the attention inner loop).
// ---------------------------------------------------------------------------
__global__ void rope_bf16(unsigned short* __restrict__ Q, unsigned short* __restrict__ K,
                          const float* __restrict__ cosT, const float* __restrict__ sinT) {
  const int row = blockIdx.x;        // 0 .. B*H*S-1
  const int t = threadIdx.x;
  const int half = t >> 7, j = t & 127;
  const int s = row & (Sc - 1);
  __shared__ float sh[2][128];
  unsigned short* buf = half ? K : Q;
  const size_t off = (size_t)row * DHc + j;
  float val = bf2f(buf[off]);
  sh[half][j] = val;
  __syncthreads();
  const float c  = cosT[s * 64 + (j & 63)];
  const float sn = sinT[s * 64 + (j & 63)];
  float rot = (j < 64) ? sh[half][2 * j + 1] : -sh[half][2 * (j - 64)];
  float r = val * c + rot * sn;
  if (!half) r *= 0.08838834764831845f * 1.4426950408889634f;  // 1/sqrt(128) * log2(e)
  buf[off] = f2bf(r);
}

// ---------------------------------------------------------------------------
// V transpose: Vbf [bh][S][128] -> Vtb [bh][128][S] (bf16).
// ---------------------------------------------------------------------------
__global__ __launch_bounds__(256)
void vtrans(const unsigned short* __restrict__ V, unsigned short* __restrict__ Vt)
{
  __shared__ __align__(16) unsigned short Ls[64][132];
  const int bid = blockIdx.x;          // bh*32 + st
  const int st = bid & 31, bh = bid >> 5;
  const int s0 = st * 64;
  const unsigned short* src = V + ((size_t)bh * Sc + s0) * DHc;
  unsigned short* dst = Vt + (size_t)bh * DHc * Sc + s0;
#pragma unroll
  for (int r = 0; r < 4; ++r) {
    int id = threadIdx.x + 256 * r;          // 0..1023
    int row = id >> 4, col = (id & 15) * 8;
    *(ushortv8*)&Ls[row][col] = *(const ushortv8*)&src[(size_t)row * DHc + col];
  }
  __syncthreads();
#pragma unroll
  for (int r = 0; r < 4; ++r) {
    int id = threadIdx.x + 256 * r;
    int d = id >> 3, scol = (id & 7) * 8;
    ushortv8 o;
#pragma unroll
    for (int jj = 0; jj < 8; ++jj) o[jj] = Ls[scol + jj][d];
    *(ushortv8*)&dst[(size_t)d * Sc + scol] = o;
  }
}

// ---------------------------------------------------------------------------
// bf16 MFMA flash attention v2.
// Scores arrive in log2-units (scale folded into Q) -> bare v_exp_f32.
// Defer-max (T13, THR=8 log2-units): skip rescale when no row's max grew.
// LDS 52KB -> 3 blocks/CU. setprio around MFMA clusters (T5).
// XCD swizzle (T1): blocks of one bh contiguous per XCD -> K/V L2 reuse.
// ---------------------------------------------------------------------------
__global__ __launch_bounds__(256)
void attn_mfma(const unsigned short* __restrict__ Qg, const unsigned short* __restrict__ Kg,
               const unsigned short* __restrict__ Vtg, unsigned short* __restrict__ Og)
{
  __shared__ __align__(16) unsigned short Ks[64][136];
  __shared__ __align__(16) unsigned short Vs[128][72];
  __shared__ __align__(16) unsigned short Ps[4][32][68];
  const int t = threadIdx.x;
  const int w = t >> 6, l = t & 63;
  const int l15 = l & 15, g = l >> 4;
  const int flat = blockIdx.x;                    // 512 blocks
  const int swz = (flat & 7) * 64 + (flat >> 3);  // XCD chunking (512%8==0)
  const int qt = swz & 15, bh = swz >> 4;         // 16 q-tiles, 32 bh
  const int q0 = qt * 128;
  const size_t kbase = (size_t)bh * Sc * DHc;   // Q,K layout [bh][S][128]
  const size_t vbase = (size_t)bh * DHc * Sc;   // Vt layout [bh][128][S]

  s16x8 qf[2][4];
#pragma unroll
  for (int mi = 0; mi < 2; ++mi)
#pragma unroll
    for (int ks = 0; ks < 4; ++ks)
      qf[mi][ks] = *(const s16x8*)&Qg[kbase + (size_t)(q0 + w * 32 + mi * 16 + l15) * DHc
                                      + ks * 32 + 8 * g];

  f32x4 acc[2][8];
#pragma unroll
  for (int mi = 0; mi < 2; ++mi)
#pragma unroll
    for (int dt = 0; dt < 8; ++dt) acc[mi][dt] = (f32x4){0.f, 0.f, 0.f, 0.f};
  float m_i[2][4], l_i[2][4];
#pragma unroll
  for (int mi = 0; mi < 2; ++mi)
#pragma unroll
    for (int r = 0; r < 4; ++r) { m_i[mi][r] = -1.0e30f; l_i[mi][r] = 0.f; }

  for (int kt0 = 0; kt0 < Sc; kt0 += 64) {
    __syncthreads();   // previous tile's LDS reads done
#pragma unroll
    for (int r = 0; r < 4; ++r) {
      int id = t + 256 * r;
      int row = id >> 4, col = (id & 15) * 8;
      *(ushortv8*)&Ks[row][col] =
          *(const ushortv8*)&Kg[kbase + (size_t)(kt0 + row) * DHc + col];
    }
#pragma unroll
    for (int r = 0; r < 4; ++r) {
      int id = t + 256 * r;
      int row = id >> 3, col = (id & 7) * 8;
      *(ushortv8*)&Vs[row][col] =
          *(const ushortv8*)&Vtg[vbase + (size_t)row * Sc + kt0 + col];
    }
    __syncthreads();

    // ---- S = Q K^T (already in log2-units)
    f32x4 sv[2][4];
#pragma unroll
    for (int mi = 0; mi < 2; ++mi)
#pragma unroll
      for (int nt = 0; nt < 4; ++nt) sv[mi][nt] = (f32x4){0.f, 0.f, 0.f, 0.f};
    __builtin_amdgcn_s_setprio(1);
#pragma unroll
    for (int nt = 0; nt < 4; ++nt) {
#pragma unroll
      for (int ks = 0; ks < 4; ++ks) {
        s16x8 bf = *(const s16x8*)&Ks[nt * 16 + l15][ks * 32 + 8 * g];
        sv[0][nt] = __builtin_amdgcn_mfma_f32_16x16x32_bf16(qf[0][ks], bf, sv[0][nt], 0, 0, 0);
        sv[1][nt] = __builtin_amdgcn_mfma_f32_16x16x32_bf16(qf[1][ks], bf, sv[1][nt], 0, 0, 0);
      }
    }
    __builtin_amdgcn_s_setprio(0);

    // ---- online softmax (rows = mi*16 + g*4 + r, cols = nt*16 + l15)
    float vmax[2][4];
    bool okb = true;
#pragma unroll
    for (int mi = 0; mi < 2; ++mi) {
#pragma unroll
      for (int r = 0; r < 4; ++r) {
        float vm = fmaxf(fmaxf(sv[mi][0][r], sv[mi][1][r]),
                         fmaxf(sv[mi][2][r], sv[mi][3][r]));
        vm = rowmax16(vm);
        vmax[mi][r] = vm;
        okb = okb && (vm - m_i[mi][r] <= 8.0f);
      }
    }
    if (__all((int)okb)) {
      // ---- stable path: keep m, no rescale (P bounded by 2^8)
#pragma unroll
      for (int mi = 0; mi < 2; ++mi) {
#pragma unroll
        for (int r = 0; r < 4; ++r) {
          float rs = 0.f;
#pragma unroll
          for (int nt = 0; nt < 4; ++nt) {
            float p = __builtin_amdgcn_exp2f(sv[mi][nt][r] - m_i[mi][r]);
            rs += p;
            Ps[w][mi * 16 + g * 4 + r][nt * 16 + l15] = f2bf(p);
          }
          l_i[mi][r] += rowsum16(rs);
        }
      }
    } else {
      // ---- rescale path
#pragma unroll
      for (int mi = 0; mi < 2; ++mi) {
#pragma unroll
        for (int r = 0; r < 4; ++r) {
          float mnew = fmaxf(m_i[mi][r], vmax[mi][r]);
          float scf = __builtin_amdgcn_exp2f(m_i[mi][r] - mnew);
          float rs = 0.f;
#pragma unroll
          for (int nt = 0; nt < 4; ++nt) {
            float p = __builtin_amdgcn_exp2f(sv[mi][nt][r] - mnew);
            rs += p;
            Ps[w][mi * 16 + g * 4 + r][nt * 16 + l15] = f2bf(p);
          }
          l_i[mi][r] = l_i[mi][r] * scf + rowsum16(rs);
          m_i[mi][r] = mnew;
#pragma unroll
          for (int dt = 0; dt < 8; ++dt) acc[mi][dt][r] *= scf;
        }
      }
    }

    // ---- P fragments (same-wave LDS round trip; in-order LDS pipe)
    s16x8 pf[2][2];
#pragma unroll
    for (int mi = 0; mi < 2; ++mi)
#pragma unroll
      for (int ks = 0; ks < 2; ++ks)
        pf[mi][ks] = *(const s16x8*)&Ps[w][mi * 16 + l15][ks * 32 + 8 * g];

    // ---- O += P V
    __builtin_amdgcn_s_setprio(1);
#pragma unroll
    for (int dt = 0; dt < 8; ++dt) {
#pragma unroll
      for (int ks = 0; ks < 2; ++ks) {
        s16x8 vf = *(const s16x8*)&Vs[dt * 16 + l15][ks * 32 + 8 * g];
        acc[0][dt] = __builtin_amdgcn_mfma_f32_16x16x32_bf16(pf[0][ks], vf, acc[0][dt], 0, 0, 0);
        acc[1][dt] = __builtin_amdgcn_mfma_f32_16x16x32_bf16(pf[1][ks], vf, acc[1][dt], 0, 0, 0);
      }
    }
    __builtin_amdgcn_s_setprio(0);
  }

  // ---- epilogue: divide by l, store bf16 to [B,S,D]
  const int b = bh >> 4, h = bh & 15;
#pragma unroll
  for (int mi = 0; mi < 2; ++mi) {
#pragma unroll
    for (int r = 0; r < 4; ++r) {
      float inv = 1.0f / l_i[mi][r];
      int srow = q0 + w * 32 + mi * 16 + g * 4 + r;
      unsigned short* dst = Og + ((size_t)(b * Sc + srow)) * Dc + h * DHc;
#pragma unroll
      for (int dt = 0; dt < 8; ++dt)
        dst[dt * 16 + l15] = f2bf(acc[mi][dt][r] * inv);
    }
  }
}

// ---------------------------------------------------------------------------
extern "C" void kernel_launch(void* const* d_in, const int* in_sizes, int n_in,
                              void* d_out, int out_size, void* d_ws, size_t ws_size,
                              hipStream_t stream) {
  const float* x    = (const float*)d_in[0];
  const float* Wqkv = (const float*)d_in[1];
  const float* bqkv = (const float*)d_in[2];
  const float* Wo   = (const float*)d_in[3];
  const float* bo   = (const float*)d_in[4];
  float* out = (float*)d_out;
  char* p = (char*)d_ws;

  // Workspace: exactly 135,266,304 B (== round-0 proven footprint)
  unsigned short* Ob  = (unsigned short*)p;  p += 16777216;   // attn out bf16 [B,S,D]
  float* cosT         = (float*)p;           p += 524288;
  float* sinT         = (float*)p;           p += 524288;
  unsigned short* xbf = (unsigned short*)p;  p += 16777216;   // x bf16 [4096][2048]
  unsigned short* Wqt = (unsigned short*)p;  p += 25165824;   // Wqkv^T bf16 [6144][2048]
  unsigned short* Wot = (unsigned short*)p;  p += 8388608;    // Wo^T bf16 [2048][2048]
  unsigned short* Qbf = (unsigned short*)p;  p += 16777216;
  unsigned short* Kbf = (unsigned short*)p;  p += 16777216;
  unsigned short* Vbf = (unsigned short*)p;  p += 16777216;
  unsigned short* Vtb = (unsigned short*)p;  p += 16777216;

  rope_table_kernel<<<(Sc * 64) / 256, 256, 0, stream>>>(cosT, sinT);

  cvt_bf16<<<(Mc * Dc) / (256 * 8), 256, 0, stream>>>(x, xbf);
  cvt_transpose<<<(N3 / 64) * (Dc / 64), 256, 0, stream>>>(Wqkv, Wqt, Dc, N3);
  cvt_transpose<<<(Dc / 64) * (Dc / 64), 256, 0, stream>>>(Wo, Wot, Dc, Dc);

  dim3 g1(N3 / 128, Mc / 128);   // 48 x 32 = 1536 blocks (%8==0)
  gemm_bt<0><<<g1, 256, 0, stream>>>(xbf, Wqt, bqkv, Qbf, Kbf, Vbf, nullptr, N3);

  rope_bf16<<<Bc * Hc * Sc, 256, 0, stream>>>(Qbf, Kbf, cosT, sinT);

  vtrans<<<Bc * Hc * (Sc / 64), 256, 0, stream>>>(Vbf, Vtb);

  attn_mfma<<<Bc * Hc * (Sc / 128), 256, 0, stream>>>(Qbf, Kbf, Vtb, Ob);

  dim3 g2(Dc / 128, Mc / 128);   // 16 x 32 = 512 blocks (%8==0)
  gemm_bt<1><<<g2, 256, 0, stream>>>(Ob, Wot, bo, nullptr, nullptr, nullptr, out, Dc);
}

// Round 6
// 449.123 us; speedup vs baseline: 1.1715x; 1.1715x over previous
//
#include <hip/hip_runtime.h>
#include <math.h>

// Problem constants (B,S,D,H fixed by the reference)
constexpr int Bc = 2, Sc = 2048, Dc = 2048, Hc = 16, DHc = 128;
constexpr int Mc = Bc * Sc;   // 4096 rows of x
constexpr int N3 = 3 * Dc;    // 6144

typedef short     s16x8  __attribute__((ext_vector_type(8)));
typedef float     f32x4  __attribute__((ext_vector_type(4)));
typedef unsigned short ushortv8 __attribute__((ext_vector_type(8)));

__device__ __forceinline__ unsigned short f2bf(float f) {
  unsigned u = __float_as_uint(f);
  u += 0x7fffu + ((u >> 16) & 1u);       // RNE
  return (unsigned short)(u >> 16);
}
__device__ __forceinline__ float bf2f(unsigned short h) {
  return __uint_as_float(((unsigned)h) << 16);
}
// 1-op f32->bf16 (RNE) via the gfx950 packed-convert (T12 recipe: no builtin).
__device__ __forceinline__ unsigned short f2bf_hw(float f) {
  unsigned r;
  asm("v_cvt_pk_bf16_f32 %0, %1, 0" : "=v"(r) : "v"(f));
  return (unsigned short)r;
}

// Async global->LDS, 16B per lane. LDS base must be wave-uniform; hardware
// writes base + lane*16. Global address is per-lane. [m97/m104 semantics]
__device__ __forceinline__ void gld_lds16(const unsigned short* g, unsigned short* l) {
  __builtin_amdgcn_global_load_lds(
      (const __attribute__((address_space(1))) void*)g,
      (__attribute__((address_space(3))) void*)l, 16, 0, 0);
}

// DPP helpers: reduction across 16-lane rows without touching the LDS pipe.
template<int CTRL>
__device__ __forceinline__ float dppf(float x) {
  return __int_as_float(
      __builtin_amdgcn_update_dpp(0, __float_as_int(x), CTRL, 0xF, 0xF, true));
}
__device__ __forceinline__ float rowmax16(float v) {
  v = fmaxf(v, dppf<0xB1>(v));    // xor1: quad_perm(1,0,3,2)
  v = fmaxf(v, dppf<0x4E>(v));    // xor2: quad_perm(2,3,0,1)
  v = fmaxf(v, dppf<0x141>(v));   // xor4: row_half_mirror
  v = fmaxf(v, dppf<0x140>(v));   // xor8: row_mirror
  return v;
}
__device__ __forceinline__ float rowsum16(float v) {
  v += dppf<0xB1>(v);
  v += dppf<0x4E>(v);
  v += dppf<0x141>(v);
  v += dppf<0x140>(v);
  return v;
}

// ---------------------------------------------------------------------------
// RoPE cos/sin tables: [S][64] each.
// ---------------------------------------------------------------------------
__global__ void rope_table_kernel(float* __restrict__ cosT, float* __restrict__ sinT) {
  int idx = blockIdx.x * 256 + threadIdx.x;   // S*64 = 131072 total
  int s = idx >> 6, j = idx & 63;
  float inv = powf(10000.0f, -(float)(2 * j) / 128.0f);
  float a = (float)s * inv;
  cosT[idx] = cosf(a);
  sinT[idx] = sinf(a);
}

// ---------------------------------------------------------------------------
// fp32 -> bf16 elementwise (x). 8 elements/thread.
// ---------------------------------------------------------------------------
__global__ void cvt_bf16(const float* __restrict__ in, unsigned short* __restrict__ outp) {
  size_t i = ((size_t)blockIdx.x * 256 + threadIdx.x) * 8;
  float4 a = *(const float4*)&in[i];
  float4 b = *(const float4*)&in[i + 4];
  ushortv8 o;
  o[0] = f2bf(a.x); o[1] = f2bf(a.y); o[2] = f2bf(a.z); o[3] = f2bf(a.w);
  o[4] = f2bf(b.x); o[5] = f2bf(b.y); o[6] = f2bf(b.z); o[7] = f2bf(b.w);
  *(ushortv8*)&outp[i] = o;
}

// ---------------------------------------------------------------------------
// fp32 [R][C] -> bf16 [C][R] transpose-convert via 64x64 LDS tile.
// ---------------------------------------------------------------------------
__global__ __launch_bounds__(256)
void cvt_transpose(const float* __restrict__ in, unsigned short* __restrict__ outp,
                   int R, int C) {
  __shared__ float Ls[64][69];
  const int nTc = C >> 6;
  const int tc = blockIdx.x % nTc, tr = blockIdx.x / nTc;
  const int r0 = tr << 6, c0 = tc << 6;
#pragma unroll
  for (int i = 0; i < 4; ++i) {
    int id = threadIdx.x + 256 * i;        // 0..1023
    int row = id >> 4, col = (id & 15) << 2;
    float4 v = *(const float4*)&in[(size_t)(r0 + row) * C + c0 + col];
    Ls[row][col] = v.x; Ls[row][col + 1] = v.y;
    Ls[row][col + 2] = v.z; Ls[row][col + 3] = v.w;
  }
  __syncthreads();
#pragma unroll
  for (int i = 0; i < 2; ++i) {
    int id = threadIdx.x + 256 * i;        // 0..511
    int crow = id >> 3, rcol = (id & 7) << 3;
    ushortv8 o;
#pragma unroll
    for (int jj = 0; jj < 8; ++jj) o[jj] = f2bf(Ls[rcol + jj][crow]);
    *(ushortv8*)&outp[(size_t)(c0 + crow) * R + r0 + rcol] = o;
  }
}

// ---------------------------------------------------------------------------
// bf16 MFMA GEMM, C[M,N] = A[M,2048] @ Bt[N,2048]^T + bias.
// m97 structure + XCD-aware block swizzle (T1; grid%8==0 -> bijective).
// ---------------------------------------------------------------------------
template<int EPI>
__global__ __launch_bounds__(256)
void gemm_bt(const unsigned short* __restrict__ A, const unsigned short* __restrict__ Bt,
             const float* __restrict__ bias, unsigned short* __restrict__ Qo,
             unsigned short* __restrict__ Ko, unsigned short* __restrict__ Vo,
             float* __restrict__ outF, int Ndim)
{
  constexpr int Kd = 2048;
  __shared__ unsigned short As[128 * 32];
  __shared__ unsigned short Bs[128 * 32];
  const int t = threadIdx.x;
  const int w = t >> 6, l = t & 63;
  const int l15 = l & 15, g = l >> 4;
  const int wr = w >> 1, wc = w & 1;
  // XCD swizzle: chunk the linearized grid per XCD (8 XCDs; nwg % 8 == 0)
  const int nwg = gridDim.x * gridDim.y;
  const int flat = blockIdx.y * gridDim.x + blockIdx.x;
  const int swz = (flat & 7) * (nwg >> 3) + (flat >> 3);
  const int m0 = (swz / gridDim.x) * 128, n0 = (swz % gridDim.x) * 128;
  const int srow = l >> 2;           // staging: row within 16-row group
  const int scol = (l & 3) * 8;      // staging: k-element offset (16B)

  f32x4 acc[4][4];
#pragma unroll
  for (int mi = 0; mi < 4; ++mi)
#pragma unroll
    for (int ni = 0; ni < 4; ++ni) acc[mi][ni] = (f32x4){0.f, 0.f, 0.f, 0.f};

  for (int k0 = 0; k0 < Kd; k0 += 32) {
    __syncthreads();                 // previous iter's LDS reads drained
#pragma unroll
    for (int j = 0; j < 2; ++j) {
      int rowg = (w * 2 + j) * 16 + srow;
      gld_lds16(&A[(size_t)(m0 + rowg) * Kd + k0 + scol], &As[(w * 2 + j) * 512]);
      gld_lds16(&Bt[(size_t)(n0 + rowg) * Kd + k0 + scol], &Bs[(w * 2 + j) * 512]);
    }
    __syncthreads();                 // vmcnt(0) drain -> LDS tile ready

    s16x8 af[4], bf[4];
#pragma unroll
    for (int mi = 0; mi < 4; ++mi)
      af[mi] = *(const s16x8*)&As[(wr * 64 + mi * 16 + l15) * 32 + g * 8];
#pragma unroll
    for (int ni = 0; ni < 4; ++ni)
      bf[ni] = *(const s16x8*)&Bs[(wc * 64 + ni * 16 + l15) * 32 + g * 8];
#pragma unroll
    for (int mi = 0; mi < 4; ++mi)
#pragma unroll
      for (int ni = 0; ni < 4; ++ni)
        acc[mi][ni] = __builtin_amdgcn_mfma_f32_16x16x32_bf16(af[mi], bf[ni], acc[mi][ni], 0, 0, 0);
  }

  if (EPI == 0) {
    const int part = n0 >> 11;
    const int h = (n0 >> 7) & 15;
    unsigned short* outp = (part == 0) ? Qo : (part == 1 ? Ko : Vo);
#pragma unroll
    for (int mi = 0; mi < 4; ++mi) {
#pragma unroll
      for (int r = 0; r < 4; ++r) {
        int row = m0 + wr * 64 + mi * 16 + g * 4 + r;
        int b_ = row >> 11, s_ = row & 2047;
        unsigned short* dst = outp + (((size_t)(b_ * Hc + h) * Sc + s_) << 7);
#pragma unroll
        for (int ni = 0; ni < 4; ++ni) {
          int col = wc * 64 + ni * 16 + l15;
          dst[col] = f2bf(acc[mi][ni][r] + bias[n0 + col]);
        }
      }
    }
  } else {
#pragma unroll
    for (int mi = 0; mi < 4; ++mi) {
#pragma unroll
      for (int r = 0; r < 4; ++r) {
        int row = m0 + wr * 64 + mi * 16 + g * 4 + r;
#pragma unroll
        for (int ni = 0; ni < 4; ++ni) {
          int col = wc * 64 + ni * 16 + l15;
          outF[(size_t)row * Ndim + n0 + col] = acc[mi][ni][r] + bias[n0 + col];
        }
      }
    }
  }
}

// ---------------------------------------------------------------------------
// In-place RoPE on bf16 Q,K. Q pre-scaled by log2(e)/sqrt(DH): folds the
// softmax scale AND the exp->exp2 conversion into Q.
// ---------------------------------------------------------------------------
__global__ void rope_bf16(unsigned short* __restrict__ Q, unsigned short* __restrict__ K,
                          const float* __restrict__ cosT, const float* __restrict__ sinT) {
  const int row = blockIdx.x;        // 0 .. B*H*S-1
  const int t = threadIdx.x;
  const int half = t >> 7, j = t & 127;
  const int s = row & (Sc - 1);
  __shared__ float sh[2][128];
  unsigned short* buf = half ? K : Q;
  const size_t off = (size_t)row * DHc + j;
  float val = bf2f(buf[off]);
  sh[half][j] = val;
  __syncthreads();
  const float c  = cosT[s * 64 + (j & 63)];
  const float sn = sinT[s * 64 + (j & 63)];
  float rot = (j < 64) ? sh[half][2 * j + 1] : -sh[half][2 * (j - 64)];
  float r = val * c + rot * sn;
  if (!half) r *= 0.08838834764831845f * 1.4426950408889634f;  // 1/sqrt(128)*log2(e)
  buf[off] = f2bf(r);
}

// ---------------------------------------------------------------------------
// V transpose: Vbf [bh][S][128] -> Vtb [bh][128][S] (bf16).
// ---------------------------------------------------------------------------
__global__ __launch_bounds__(256)
void vtrans(const unsigned short* __restrict__ V, unsigned short* __restrict__ Vt)
{
  __shared__ __align__(16) unsigned short Ls[64][132];
  const int bid = blockIdx.x;          // bh*32 + st
  const int st = bid & 31, bh = bid >> 5;
  const int s0 = st * 64;
  const unsigned short* src = V + ((size_t)bh * Sc + s0) * DHc;
  unsigned short* dst = Vt + (size_t)bh * DHc * Sc + s0;
#pragma unroll
  for (int r = 0; r < 4; ++r) {
    int id = threadIdx.x + 256 * r;          // 0..1023
    int row = id >> 4, col = (id & 15) * 8;
    *(ushortv8*)&Ls[row][col] = *(const ushortv8*)&src[(size_t)row * DHc + col];
  }
  __syncthreads();
#pragma unroll
  for (int r = 0; r < 4; ++r) {
    int id = threadIdx.x + 256 * r;
    int d = id >> 3, scol = (id & 7) * 8;
    ushortv8 o;
#pragma unroll
    for (int jj = 0; jj < 8; ++jj) o[jj] = Ls[scol + jj][d];
    *(ushortv8*)&dst[(size_t)d * Sc + scol] = o;
  }
}

// ---------------------------------------------------------------------------
// bf16 MFMA flash attention v3.
// - single-path online softmax (r3 structure; low VGPR)
// - scores in log2-units (scale folded into Q) -> bare v_exp_f32
// - K/V staged via global_load_lds (linear LDS dest) with XOR-swizzled
//   global source + XOR-swizzled reads (rule #21 pattern): col16 ^= row&7.
//   Invariant: LDS[row][c] = SRC[row][c^(row&7)]; read XOR cancels it.
//   Unpadded Ks[64][128], Vs[128][64]; b128 reads stay at 2-way minimum.
// - P->bf16 stores use 1-op v_cvt_pk_bf16_f32.
// LDS 50176 B. setprio around MFMA clusters (T5). XCD swizzle (T1).
// ---------------------------------------------------------------------------
__global__ __launch_bounds__(256)
void attn_mfma(const unsigned short* __restrict__ Qg, const unsigned short* __restrict__ Kg,
               const unsigned short* __restrict__ Vtg, unsigned short* __restrict__ Og)
{
  __shared__ __align__(16) unsigned short Ks[64 * 128];
  __shared__ __align__(16) unsigned short Vs[128 * 64];
  __shared__ __align__(16) unsigned short Ps[4][32][68];
  const int t = threadIdx.x;
  const int w = t >> 6, l = t & 63;
  const int l15 = l & 15, g = l >> 4;
  const int flat = blockIdx.x;                    // 512 blocks
  const int swz = (flat & 7) * 64 + (flat >> 3);  // XCD chunking (512%8==0)
  const int qt = swz & 15, bh = swz >> 4;         // 16 q-tiles, 32 bh
  const int q0 = qt * 128;
  const size_t kbase = (size_t)bh * Sc * DHc;   // Q,K layout [bh][S][128]
  const size_t vbase = (size_t)bh * DHc * Sc;   // Vt layout [bh][128][S]

  // Staging geometry (per wave, 4 instrs each for K and V):
  //   K: chunk=w*4+j covers rows chunk*4..+3; lane l -> row chunk*4+(l>>4),
  //      src col16 = (l&15) ^ (row&7)  [inverse swizzle]
  //   V: chunk covers d-rows chunk*8..+7; lane l -> row chunk*8+(l>>3),
  //      src col16 = (l&7) ^ (row&7)
  const int krow_in = (l >> 4);          // 0..3
  const int vrow_in = (l >> 3);          // 0..7

  s16x8 qf[2][4];
#pragma unroll
  for (int mi = 0; mi < 2; ++mi)
#pragma unroll
    for (int ks = 0; ks < 4; ++ks)
      qf[mi][ks] = *(const s16x8*)&Qg[kbase + (size_t)(q0 + w * 32 + mi * 16 + l15) * DHc
                                      + ks * 32 + 8 * g];

  f32x4 acc[2][8];
#pragma unroll
  for (int mi = 0; mi < 2; ++mi)
#pragma unroll
    for (int dt = 0; dt < 8; ++dt) acc[mi][dt] = (f32x4){0.f, 0.f, 0.f, 0.f};
  float m_i[2][4], l_i[2][4];
#pragma unroll
  for (int mi = 0; mi < 2; ++mi)
#pragma unroll
    for (int r = 0; r < 4; ++r) { m_i[mi][r] = -1.0e30f; l_i[mi][r] = 0.f; }

  for (int kt0 = 0; kt0 < Sc; kt0 += 64) {
    __syncthreads();   // previous tile's LDS reads done
#pragma unroll
    for (int j = 0; j < 4; ++j) {
      int chunk = w * 4 + j;                 // 0..15
      int krow = chunk * 4 + krow_in;        // 0..63
      int kc16 = (l15) ^ (krow & 7);
      gld_lds16(&Kg[kbase + (size_t)(kt0 + krow) * DHc + kc16 * 8], &Ks[chunk * 512]);
      int vrow = chunk * 8 + vrow_in;        // 0..127
      int vc16 = (l & 7) ^ (vrow & 7);
      gld_lds16(&Vtg[vbase + (size_t)vrow * Sc + kt0 + vc16 * 8], &Vs[chunk * 512]);
    }
    __syncthreads();   // vmcnt(0) drain -> tiles ready

    // ---- S = Q K^T (log2-units). Swizzled read: col16 = (4ks+g)^(l15&7)
    f32x4 sv[2][4];
#pragma unroll
    for (int mi = 0; mi < 2; ++mi)
#pragma unroll
      for (int nt = 0; nt < 4; ++nt) sv[mi][nt] = (f32x4){0.f, 0.f, 0.f, 0.f};
    __builtin_amdgcn_s_setprio(1);
#pragma unroll
    for (int nt = 0; nt < 4; ++nt) {
#pragma unroll
      for (int ks = 0; ks < 4; ++ks) {
        int c16 = (4 * ks + g) ^ (l15 & 7);
        s16x8 bf = *(const s16x8*)&Ks[(nt * 16 + l15) * 128 + c16 * 8];
        sv[0][nt] = __builtin_amdgcn_mfma_f32_16x16x32_bf16(qf[0][ks], bf, sv[0][nt], 0, 0, 0);
        sv[1][nt] = __builtin_amdgcn_mfma_f32_16x16x32_bf16(qf[1][ks], bf, sv[1][nt], 0, 0, 0);
      }
    }
    __builtin_amdgcn_s_setprio(0);

    // ---- online softmax (rows = mi*16 + g*4 + r, cols = nt*16 + l15)
#pragma unroll
    for (int mi = 0; mi < 2; ++mi) {
#pragma unroll
      for (int r = 0; r < 4; ++r) {
        float vm = fmaxf(fmaxf(sv[mi][0][r], sv[mi][1][r]),
                         fmaxf(sv[mi][2][r], sv[mi][3][r]));
        vm = rowmax16(vm);
        float mnew = fmaxf(m_i[mi][r], vm);
        float scf = __builtin_amdgcn_exp2f(m_i[mi][r] - mnew);
        float rs = 0.f;
#pragma unroll
        for (int nt = 0; nt < 4; ++nt) {
          float p = __builtin_amdgcn_exp2f(sv[mi][nt][r] - mnew);
          rs += p;
          Ps[w][mi * 16 + g * 4 + r][nt * 16 + l15] = f2bf_hw(p);
        }
        l_i[mi][r] = l_i[mi][r] * scf + rowsum16(rs);
        m_i[mi][r] = mnew;
#pragma unroll
        for (int dt = 0; dt < 8; ++dt) acc[mi][dt][r] *= scf;
      }
    }

    // ---- P fragments (same-wave LDS round trip; in-order LDS pipe)
    s16x8 pf[2][2];
#pragma unroll
    for (int mi = 0; mi < 2; ++mi)
#pragma unroll
      for (int ks = 0; ks < 2; ++ks)
        pf[mi][ks] = *(const s16x8*)&Ps[w][mi * 16 + l15][ks * 32 + 8 * g];

    // ---- O += P V ; swizzled V read: col16 = (4ks+g)^(l15&7)
    __builtin_amdgcn_s_setprio(1);
#pragma unroll
    for (int dt = 0; dt < 8; ++dt) {
#pragma unroll
      for (int ks = 0; ks < 2; ++ks) {
        int c16 = (4 * ks + g) ^ (l15 & 7);
        s16x8 vf = *(const s16x8*)&Vs[(dt * 16 + l15) * 64 + c16 * 8];
        acc[0][dt] = __builtin_amdgcn_mfma_f32_16x16x32_bf16(pf[0][ks], vf, acc[0][dt], 0, 0, 0);
        acc[1][dt] = __builtin_amdgcn_mfma_f32_16x16x32_bf16(pf[1][ks], vf, acc[1][dt], 0, 0, 0);
      }
    }
    __builtin_amdgcn_s_setprio(0);
  }

  // ---- epilogue: divide by l, store bf16 to [B,S,D]
  const int b = bh >> 4, h = bh & 15;
#pragma unroll
  for (int mi = 0; mi < 2; ++mi) {
#pragma unroll
    for (int r = 0; r < 4; ++r) {
      float inv = 1.0f / l_i[mi][r];
      int srow = q0 + w * 32 + mi * 16 + g * 4 + r;
      unsigned short* dst = Og + ((size_t)(b * Sc + srow)) * Dc + h * DHc;
#pragma unroll
      for (int dt = 0; dt < 8; ++dt)
        dst[dt * 16 + l15] = f2bf_hw(acc[mi][dt][r] * inv);
    }
  }
}

// ---------------------------------------------------------------------------
extern "C" void kernel_launch(void* const* d_in, const int* in_sizes, int n_in,
                              void* d_out, int out_size, void* d_ws, size_t ws_size,
                              hipStream_t stream) {
  const float* x    = (const float*)d_in[0];
  const float* Wqkv = (const float*)d_in[1];
  const float* bqkv = (const float*)d_in[2];
  const float* Wo   = (const float*)d_in[3];
  const float* bo   = (const float*)d_in[4];
  float* out = (float*)d_out;
  char* p = (char*)d_ws;

  // Workspace: exactly 135,266,304 B (== round-0 proven footprint)
  unsigned short* Ob  = (unsigned short*)p;  p += 16777216;   // attn out bf16 [B,S,D]
  float* cosT         = (float*)p;           p += 524288;
  float* sinT         = (float*)p;           p += 524288;
  unsigned short* xbf = (unsigned short*)p;  p += 16777216;   // x bf16 [4096][2048]
  unsigned short* Wqt = (unsigned short*)p;  p += 25165824;   // Wqkv^T bf16 [6144][2048]
  unsigned short* Wot = (unsigned short*)p;  p += 8388608;    // Wo^T bf16 [2048][2048]
  unsigned short* Qbf = (unsigned short*)p;  p += 16777216;
  unsigned short* Kbf = (unsigned short*)p;  p += 16777216;
  unsigned short* Vbf = (unsigned short*)p;  p += 16777216;
  unsigned short* Vtb = (unsigned short*)p;  p += 16777216;

  rope_table_kernel<<<(Sc * 64) / 256, 256, 0, stream>>>(cosT, sinT);

  cvt_bf16<<<(Mc * Dc) / (256 * 8), 256, 0, stream>>>(x, xbf);
  cvt_transpose<<<(N3 / 64) * (Dc / 64), 256, 0, stream>>>(Wqkv, Wqt, Dc, N3);
  cvt_transpose<<<(Dc / 64) * (Dc / 64), 256, 0, stream>>>(Wo, Wot, Dc, Dc);

  dim3 g1(N3 / 128, Mc / 128);   // 48 x 32 = 1536 blocks (%8==0)
  gemm_bt<0><<<g1, 256, 0, stream>>>(xbf, Wqt, bqkv, Qbf, Kbf, Vbf, nullptr, N3);

  rope_bf16<<<Bc * Hc * Sc, 256, 0, stream>>>(Qbf, Kbf, cosT, sinT);

  vtrans<<<Bc * Hc * (Sc / 64), 256, 0, stream>>>(Vbf, Vtb);

  attn_mfma<<<Bc * Hc * (Sc / 128), 256, 0, stream>>>(Qbf, Kbf, Vtb, Ob);

  dim3 g2(Dc / 128, Mc / 128);   // 16 x 32 = 512 blocks (%8==0)
  gemm_bt<1><<<g2, 256, 0, stream>>>(Ob, Wot, bo, nullptr, nullptr, nullptr, out, Dc);
}